// Round 1
// baseline (2148.019 us; speedup 1.0000x reference)
//
#include <hip/hip_runtime.h>
#include <stdint.h>

// Sparse 5x5x5 conv (N=500k, 32->32ch, 125 taps) + BatchNorm + ELU + Linear.
// Strategy: bf16 MFMA gather-conv over all 125 taps (zero-fill invalid),
// accumulation fp32. b_conv is mathematically canceled by BN mean-subtract.

#define NV 500000
#define KT 125
#define CH 32
#define EPSBN 1e-5f

typedef __attribute__((ext_vector_type(8))) short short8;   // 8 x bf16 frag
typedef __attribute__((ext_vector_type(4))) float f32x4;    // MFMA C/D frag

__device__ __forceinline__ unsigned short f2bf(float f) {
    union { float f; unsigned int u; } v; v.f = f;
    unsigned int u = v.u;
    return (unsigned short)((u + 0x7fffu + ((u >> 16) & 1u)) >> 16);  // RNE
}

// K1: convert x -> bf16, build W_conv in B-fragment layout, zero stats.
// wf layout: frag(k, h, lane, j) at ((k*2+h)*64 + lane)*8 + j
//   holds W_conv[k][ (lane>>4)*8 + j ][ h*16 + (lane&15) ]
__global__ void k_prep(const float* __restrict__ x, const float* __restrict__ Wc,
                       unsigned short* __restrict__ xb, unsigned short* __restrict__ wf,
                       float* __restrict__ stats) {
    int tid = blockIdx.x * blockDim.x + threadIdx.x;
    if (blockIdx.x == 0 && threadIdx.x < 64) stats[threadIdx.x] = 0.0f;  // sum[32], sumsq[32]
    if (tid < KT * 2 * 64) {
        int k = tid >> 7;
        int rem = tid & 127;
        int h = rem >> 6;
        int l = rem & 63;
        int kd0 = (l >> 4) * 8;
        int cc = h * 16 + (l & 15);
        #pragma unroll
        for (int j = 0; j < 8; j++)
            wf[tid * 8 + j] = f2bf(Wc[(k * CH + kd0 + j) * CH + cc]);
    }
    int stride = gridDim.x * blockDim.x;
    for (int i = tid; i < NV * CH; i += stride) xb[i] = f2bf(x[i]);
}

// K2: gather-conv. Wave handles 8 tiles of 16 voxels (128 voxels).
// mfma_f32_16x16x32_bf16: A[m=lane&15][k=(lane>>4)*8+j] = x[nbr[v,k]] row,
// B from wf (pre-laid-out), D col=lane&15 row=(lane>>4)*4+reg.
__global__ __launch_bounds__(256) void
k_conv(const unsigned short* __restrict__ xb, const int* __restrict__ nbr,
       const unsigned short* __restrict__ wf, float* __restrict__ co,
       float* __restrict__ stats) {
    const int lane = threadIdx.x & 63;
    const int wv = threadIdx.x >> 6;
    const int m = lane & 15;
    const int q = lane >> 4;
    const int vbase = (blockIdx.x * 4 + wv) * 128;

    f32x4 acc[8][2];
    #pragma unroll
    for (int t = 0; t < 8; t++)
        for (int h = 0; h < 2; h++)
            acc[t][h] = f32x4{0.f, 0.f, 0.f, 0.f};

    bool tval[8];
    int rbase[8];
    #pragma unroll
    for (int t = 0; t < 8; t++) {
        tval[t] = (vbase + t * 16) < NV;           // NV%16==0: tiles uniformly valid
        rbase[t] = (vbase + t * 16 + m) * KT;
    }
    const short8 zero8 = {0, 0, 0, 0, 0, 0, 0, 0};

    for (int k = 0; k < KT; k++) {
        short8 b0 = *(const short8*)(wf + (size_t)(k * 128 + lane) * 8);
        short8 b1 = *(const short8*)(wf + (size_t)(k * 128 + 64 + lane) * 8);
        #pragma unroll
        for (int t = 0; t < 8; t++) {
            int idx = tval[t] ? nbr[rbase[t] + k] : -1;
            short8 a = zero8;
            if (idx >= 0) a = *(const short8*)(xb + (size_t)idx * CH + q * 8);
            acc[t][0] = __builtin_amdgcn_mfma_f32_16x16x32_bf16(a, b0, acc[t][0], 0, 0, 0);
            acc[t][1] = __builtin_amdgcn_mfma_f32_16x16x32_bf16(a, b1, acc[t][1], 0, 0, 0);
        }
    }

    // Store conv output (pre-BN) into d_out; accumulate BN stats.
    float s0 = 0.f, s1 = 0.f, q0 = 0.f, q1 = 0.f;
    #pragma unroll
    for (int t = 0; t < 8; t++) {
        if (!tval[t]) continue;
        int v0 = vbase + t * 16 + q * 4;
        #pragma unroll
        for (int r = 0; r < 4; r++) {
            float a0 = acc[t][0][r], a1 = acc[t][1][r];
            co[(size_t)(v0 + r) * CH + m] = a0;
            co[(size_t)(v0 + r) * CH + 16 + m] = a1;
            s0 += a0; q0 += a0 * a0;
            s1 += a1; q1 += a1 * a1;
        }
    }
    // reduce across the 4 quads (lanes sharing lane&15)
    s0 += __shfl_xor(s0, 16); s0 += __shfl_xor(s0, 32);
    s1 += __shfl_xor(s1, 16); s1 += __shfl_xor(s1, 32);
    q0 += __shfl_xor(q0, 16); q0 += __shfl_xor(q0, 32);
    q1 += __shfl_xor(q1, 16); q1 += __shfl_xor(q1, 32);
    if (q == 0) {
        atomicAdd(&stats[m],      s0);
        atomicAdd(&stats[16 + m], s1);
        atomicAdd(&stats[32 + m], q0);
        atomicAdd(&stats[48 + m], q1);
    }
}

// K3: finalize BN scale/shift. stats[64..95]=scale, stats[96..127]=shift.
__global__ void k_final(const float* __restrict__ gamma, const float* __restrict__ beta,
                        float* __restrict__ stats) {
    int c = threadIdx.x;
    if (c < CH) {
        float mean = stats[c] * (1.0f / NV);
        float var = stats[32 + c] * (1.0f / NV) - mean * mean;
        float sc = gamma[c] * rsqrtf(var + EPSBN);
        stats[64 + c] = sc;
        stats[96 + c] = beta[c] - mean * sc;
    }
}

// K4: in-place BN + ELU + (e @ W_lin^T + b_lin) on d_out.
// lane&31 = out channel; 2 voxels per wave per iter; e_j broadcast via shfl.
__global__ __launch_bounds__(256) void
k_epi(float* __restrict__ io, const float* __restrict__ Wlin,
      const float* __restrict__ blin, const float* __restrict__ stats) {
    __shared__ float wt[32 * 33];   // wt[j*33+c] = Wlin[c*32+j] (padded: no bank conflict)
    __shared__ float ssc[32], ssh[32], sb[32];
    int tid = threadIdx.x;
    for (int i = tid; i < 1024; i += blockDim.x) {
        int cc = i & 31, j = i >> 5;
        wt[j * 33 + cc] = Wlin[cc * 32 + j];
    }
    if (tid < 32) { ssc[tid] = stats[64 + tid]; ssh[tid] = stats[96 + tid]; sb[tid] = blin[tid]; }
    __syncthreads();

    const int c = tid & 31;
    const int vstep = (gridDim.x * blockDim.x) >> 5;
    for (int v = (blockIdx.x * blockDim.x + tid) >> 5; v < NV; v += vstep) {
        float e = io[(size_t)v * CH + c];
        e = e * ssc[c] + ssh[c];
        e = e > 0.0f ? e : (__expf(e) - 1.0f);       // ELU alpha=1
        float acc = sb[c];
        #pragma unroll
        for (int j = 0; j < 32; j++) {
            float ej = __shfl(e, (tid & 32) | j, 64);
            acc += ej * wt[j * 33 + c];
        }
        io[(size_t)v * CH + c] = acc;
    }
}

extern "C" void kernel_launch(void* const* d_in, const int* in_sizes, int n_in,
                              void* d_out, int out_size, void* d_ws, size_t ws_size,
                              hipStream_t stream) {
    const float* x     = (const float*)d_in[0];
    const int*   nbr   = (const int*)d_in[1];
    const float* Wc    = (const float*)d_in[2];
    // d_in[3] = b_conv: exactly canceled by BatchNorm mean subtraction — unused.
    const float* gamma = (const float*)d_in[4];
    const float* beta  = (const float*)d_in[5];
    const float* Wlin  = (const float*)d_in[6];
    const float* blin  = (const float*)d_in[7];
    float* out = (float*)d_out;

    char* ws = (char*)d_ws;
    unsigned short* xb = (unsigned short*)ws;                              // 32 MB
    unsigned short* wf = (unsigned short*)(ws + (size_t)NV * CH * 2);      // 256 KB
    float* stats = (float*)(ws + (size_t)NV * CH * 2 + (size_t)KT * 128 * 8 * 2);  // 512 B

    hipLaunchKernelGGL(k_prep, dim3(4096), dim3(256), 0, stream, x, Wc, xb, wf, stats);
    hipLaunchKernelGGL(k_conv, dim3((NV + 511) / 512), dim3(256), 0, stream, xb, nbr, wf, out, stats);
    hipLaunchKernelGGL(k_final, dim3(1), dim3(64), 0, stream, gamma, beta, stats);
    hipLaunchKernelGGL(k_epi, dim3(1024), dim3(256), 0, stream, out, Wlin, blin, stats);
}

// Round 2
// 975.544 us; speedup vs baseline: 2.2019x; 2.2019x over previous
//
#include <hip/hip_runtime.h>
#include <stdint.h>

// Sparse 5x5x5 conv (N=500k, 32->32ch, 125 taps) + BatchNorm + ELU + Linear.
// bf16 MFMA gather-conv, fp32 accum. b_conv canceled by BN mean-subtract.
// R1 fix: nbr rows loaded ONCE per voxel in 16-tap register chunks + shfl
// distribution (kills the 4 GB L2-miss re-fetch of nbr lines).

#define NV 500000
#define KT 125
#define CH 32
#define EPSBN 1e-5f

typedef __attribute__((ext_vector_type(8))) short short8;   // 8 x bf16 frag
typedef __attribute__((ext_vector_type(4))) float f32x4;    // MFMA C/D frag

__device__ __forceinline__ unsigned short f2bf(float f) {
    union { float f; unsigned int u; } v; v.f = f;
    unsigned int u = v.u;
    return (unsigned short)((u + 0x7fffu + ((u >> 16) & 1u)) >> 16);  // RNE
}

// K1: convert x -> bf16 (vectorized), build W_conv B-fragment layout, zero stats.
// wf frag(k, h, lane, j) at ((k*2+h)*64 + lane)*8 + j
//   = W_conv[k][ (lane>>4)*8 + j ][ h*16 + (lane&15) ]
__global__ __launch_bounds__(256) void
k_prep(const float* __restrict__ x, const float* __restrict__ Wc,
       unsigned short* __restrict__ xb, unsigned short* __restrict__ wf,
       float* __restrict__ stats) {
    int tid = blockIdx.x * blockDim.x + threadIdx.x;
    if (blockIdx.x == 0 && threadIdx.x < 64) stats[threadIdx.x] = 0.0f;
    if (tid < KT * 2 * 64) {
        int k = tid >> 7;
        int rem = tid & 127;
        int h = rem >> 6;
        int l = rem & 63;
        int kd0 = (l >> 4) * 8;
        int cc = h * 16 + (l & 15);
        #pragma unroll
        for (int j = 0; j < 8; j++)
            wf[tid * 8 + j] = f2bf(Wc[(k * CH + kd0 + j) * CH + cc]);
    }
    size_t i8 = (size_t)tid * 8;
    if (i8 < (size_t)NV * CH) {           // NV*CH = 16e6, divisible by 8
        float4 a = *(const float4*)(x + i8);
        float4 b = *(const float4*)(x + i8 + 4);
        short8 o;
        o[0] = (short)f2bf(a.x); o[1] = (short)f2bf(a.y);
        o[2] = (short)f2bf(a.z); o[3] = (short)f2bf(a.w);
        o[4] = (short)f2bf(b.x); o[5] = (short)f2bf(b.y);
        o[6] = (short)f2bf(b.z); o[7] = (short)f2bf(b.w);
        *(short8*)(xb + i8) = o;
    }
}

// One 16-tap chunk (CNT taps consumed): 4 dword loads/lane cover the whole
// 64B tap window of each of the 16 rows; tap j's index reaches all 4 q-lanes
// of its row via __shfl (ds_bpermute).
template<int CNT>
__device__ __forceinline__ void
conv_chunk(int kc, const int* __restrict__ nbr, const unsigned short* __restrict__ xb,
           const unsigned short* __restrict__ wf, f32x4 (&acc)[4][2],
           const int (&rbase)[4], int m, int q, int lane) {
    int nb[4][4];
    #pragma unroll
    for (int t = 0; t < 4; t++) {
        #pragma unroll
        for (int r = 0; r < 4; r++) {
            int k = kc + r * 4 + q;
            nb[t][r] = nbr[rbase[t] + (k > 124 ? 124 : k)];
        }
    }
    #pragma unroll
    for (int j = 0; j < CNT; j++) {
        const int k = kc + j;
        short8 b0 = *(const short8*)(wf + (size_t)(k * 128 + lane) * 8);
        short8 b1 = *(const short8*)(wf + (size_t)(k * 128 + 64 + lane) * 8);
        #pragma unroll
        for (int t = 0; t < 4; t++) {
            int idx = __shfl(nb[t][j >> 2], ((j & 3) << 4) | m, 64);
            short8 a = {0, 0, 0, 0, 0, 0, 0, 0};
            if (idx >= 0) a = *(const short8*)(xb + (size_t)idx * CH + q * 8);
            acc[t][0] = __builtin_amdgcn_mfma_f32_16x16x32_bf16(a, b0, acc[t][0], 0, 0, 0);
            acc[t][1] = __builtin_amdgcn_mfma_f32_16x16x32_bf16(a, b1, acc[t][1], 0, 0, 0);
        }
    }
}

// K2: gather-conv. Wave = 4 tiles of 16 voxels (64 voxels).
// mfma_f32_16x16x32_bf16: A[m=lane&15][k=(lane>>4)*8+j], D col=lane&15,
// row=(lane>>4)*4+reg.
__global__ __launch_bounds__(256) void
k_conv(const unsigned short* __restrict__ xb, const int* __restrict__ nbr,
       const unsigned short* __restrict__ wf, float* __restrict__ co,
       float* __restrict__ stats) {
    const int lane = threadIdx.x & 63;
    const int wv = threadIdx.x >> 6;
    const int m = lane & 15;
    const int q = lane >> 4;
    const int vbase = (blockIdx.x * 4 + wv) * 64;

    f32x4 acc[4][2];
    #pragma unroll
    for (int t = 0; t < 4; t++)
        for (int h = 0; h < 2; h++)
            acc[t][h] = f32x4{0.f, 0.f, 0.f, 0.f};

    bool tval[4];
    int rbase[4];
    #pragma unroll
    for (int t = 0; t < 4; t++) {
        tval[t] = (vbase + t * 16) < NV;            // NV%16==0: uniform per tile
        rbase[t] = tval[t] ? (vbase + t * 16 + m) * KT : 0;  // invalid: dummy in-bounds
    }

    #pragma unroll
    for (int c = 0; c < 7; c++)
        conv_chunk<16>(c * 16, nbr, xb, wf, acc, rbase, m, q, lane);
    conv_chunk<13>(112, nbr, xb, wf, acc, rbase, m, q, lane);

    float s0 = 0.f, s1 = 0.f, q0 = 0.f, q1 = 0.f;
    #pragma unroll
    for (int t = 0; t < 4; t++) {
        if (!tval[t]) continue;
        int v0 = vbase + t * 16 + q * 4;
        #pragma unroll
        for (int r = 0; r < 4; r++) {
            float a0 = acc[t][0][r], a1 = acc[t][1][r];
            co[(size_t)(v0 + r) * CH + m] = a0;
            co[(size_t)(v0 + r) * CH + 16 + m] = a1;
            s0 += a0; q0 += a0 * a0;
            s1 += a1; q1 += a1 * a1;
        }
    }
    s0 += __shfl_xor(s0, 16); s0 += __shfl_xor(s0, 32);
    s1 += __shfl_xor(s1, 16); s1 += __shfl_xor(s1, 32);
    q0 += __shfl_xor(q0, 16); q0 += __shfl_xor(q0, 32);
    q1 += __shfl_xor(q1, 16); q1 += __shfl_xor(q1, 32);
    if (q == 0) {
        atomicAdd(&stats[m],      s0);
        atomicAdd(&stats[16 + m], s1);
        atomicAdd(&stats[32 + m], q0);
        atomicAdd(&stats[48 + m], q1);
    }
}

// K3: finalize BN scale/shift. stats[64..95]=scale, stats[96..127]=shift.
__global__ void k_final(const float* __restrict__ gamma, const float* __restrict__ beta,
                        float* __restrict__ stats) {
    int c = threadIdx.x;
    if (c < CH) {
        float mean = stats[c] * (1.0f / NV);
        float var = stats[32 + c] * (1.0f / NV) - mean * mean;
        float sc = gamma[c] * rsqrtf(var + EPSBN);
        stats[64 + c] = sc;
        stats[96 + c] = beta[c] - mean * sc;
    }
}

// K4: in-place BN + ELU + (e @ W_lin^T + b_lin) on d_out.
__global__ __launch_bounds__(256) void
k_epi(float* __restrict__ io, const float* __restrict__ Wlin,
      const float* __restrict__ blin, const float* __restrict__ stats) {
    __shared__ float wt[32 * 33];
    __shared__ float ssc[32], ssh[32], sb[32];
    int tid = threadIdx.x;
    for (int i = tid; i < 1024; i += blockDim.x) {
        int cc = i & 31, j = i >> 5;
        wt[j * 33 + cc] = Wlin[cc * 32 + j];
    }
    if (tid < 32) { ssc[tid] = stats[64 + tid]; ssh[tid] = stats[96 + tid]; sb[tid] = blin[tid]; }
    __syncthreads();

    const int c = tid & 31;
    const int vstep = (gridDim.x * blockDim.x) >> 5;
    for (int v = (blockIdx.x * blockDim.x + tid) >> 5; v < NV; v += vstep) {
        float e = io[(size_t)v * CH + c];
        e = e * ssc[c] + ssh[c];
        e = e > 0.0f ? e : (__expf(e) - 1.0f);
        float acc = sb[c];
        #pragma unroll
        for (int j = 0; j < 32; j++) {
            float ej = __shfl(e, (tid & 32) | j, 64);
            acc += ej * wt[j * 33 + c];
        }
        io[(size_t)v * CH + c] = acc;
    }
}

extern "C" void kernel_launch(void* const* d_in, const int* in_sizes, int n_in,
                              void* d_out, int out_size, void* d_ws, size_t ws_size,
                              hipStream_t stream) {
    const float* x     = (const float*)d_in[0];
    const int*   nbr   = (const int*)d_in[1];
    const float* Wc    = (const float*)d_in[2];
    // d_in[3] = b_conv: canceled by BN mean subtraction.
    const float* gamma = (const float*)d_in[4];
    const float* beta  = (const float*)d_in[5];
    const float* Wlin  = (const float*)d_in[6];
    const float* blin  = (const float*)d_in[7];
    float* out = (float*)d_out;

    char* ws = (char*)d_ws;
    unsigned short* xb = (unsigned short*)ws;                              // 32 MB
    unsigned short* wf = (unsigned short*)(ws + (size_t)NV * CH * 2);      // 256 KB
    float* stats = (float*)(ws + (size_t)NV * CH * 2 + (size_t)KT * 128 * 8 * 2);

    int prep_blocks = (int)(((size_t)NV * CH / 8 + 255) / 256);            // 7813
    hipLaunchKernelGGL(k_prep, dim3(prep_blocks), dim3(256), 0, stream, x, Wc, xb, wf, stats);
    hipLaunchKernelGGL(k_conv, dim3((NV + 255) / 256), dim3(256), 0, stream, xb, nbr, wf, out, stats);
    hipLaunchKernelGGL(k_final, dim3(1), dim3(64), 0, stream, gamma, beta, stats);
    hipLaunchKernelGGL(k_epi, dim3(1024), dim3(256), 0, stream, out, Wlin, blin, stats);
}

// Round 3
// 737.016 us; speedup vs baseline: 2.9145x; 1.3236x over previous
//
#include <hip/hip_runtime.h>
#include <stdint.h>

// Sparse 5x5x5 conv (N=500k, 32->32ch, 125 taps) + BatchNorm + ELU + Linear.
// bf16 MFMA gather-conv, fp32 accum. b_conv canceled by BN mean-subtract.
// R2: explicit 2-deep software pipeline in k_conv (refill group G+2 while
// consuming G) to raise gather MLP 6.6 -> ~100+/CU; k_epi linear via MFMA.

#define NV 500000
#define KT 125
#define CH 32
#define EPSBN 1e-5f
#define NTILES (NV / 16)   // 31250

typedef __attribute__((ext_vector_type(8))) short short8;   // 8 x bf16 frag
typedef __attribute__((ext_vector_type(4))) float f32x4;    // MFMA C/D frag

__device__ __forceinline__ unsigned short f2bf(float f) {
    union { float f; unsigned int u; } v; v.f = f;
    unsigned int u = v.u;
    return (unsigned short)((u + 0x7fffu + ((u >> 16) & 1u)) >> 16);  // RNE
}

// K1: x -> bf16 (vectorized); W_conv B-frags (wf); W_lin^T B-frags (wl); zero stats.
// wf frag(k, h, lane, j) = W_conv[k][ (lane>>4)*8 + j ][ h*16 + (lane&15) ]
// wl frag(h, lane, j)    = W_lin [ h*16 + (lane&15) ][ (lane>>4)*8 + j ]
__global__ __launch_bounds__(256) void
k_prep(const float* __restrict__ x, const float* __restrict__ Wc,
       const float* __restrict__ Wlin,
       unsigned short* __restrict__ xb, unsigned short* __restrict__ wf,
       unsigned short* __restrict__ wl, float* __restrict__ stats) {
    int tid = blockIdx.x * blockDim.x + threadIdx.x;
    if (blockIdx.x == 0 && threadIdx.x < 64) stats[threadIdx.x] = 0.0f;
    if (tid < KT * 2 * 64) {
        int k = tid >> 7;
        int rem = tid & 127;
        int h = rem >> 6;
        int l = rem & 63;
        int kd0 = (l >> 4) * 8;
        int cc = h * 16 + (l & 15);
        #pragma unroll
        for (int j = 0; j < 8; j++)
            wf[tid * 8 + j] = f2bf(Wc[(k * CH + kd0 + j) * CH + cc]);
    } else if (tid < KT * 2 * 64 + 128) {
        int t2 = tid - KT * 2 * 64;
        int h = t2 >> 6;
        int l = t2 & 63;
        int n = l & 15;
        int kd0 = (l >> 4) * 8;
        #pragma unroll
        for (int j = 0; j < 8; j++)
            wl[t2 * 8 + j] = f2bf(Wlin[(h * 16 + n) * CH + kd0 + j]);
    }
    size_t i8 = (size_t)tid * 8;
    if (i8 < (size_t)NV * CH) {
        float4 a = *(const float4*)(x + i8);
        float4 b = *(const float4*)(x + i8 + 4);
        short8 o;
        o[0] = (short)f2bf(a.x); o[1] = (short)f2bf(a.y);
        o[2] = (short)f2bf(a.z); o[3] = (short)f2bf(a.w);
        o[4] = (short)f2bf(b.x); o[5] = (short)f2bf(b.y);
        o[6] = (short)f2bf(b.z); o[7] = (short)f2bf(b.w);
        *(short8*)(xb + i8) = o;
    }
}

// ---- k_conv pipeline helpers (all force-inlined, constant-folded) ----

__device__ __forceinline__ void
load_nb(int w, const int* __restrict__ nbr, const int (&rbase)[4], int q, int (&out)[4][4]) {
    #pragma unroll
    for (int t = 0; t < 4; t++) {
        #pragma unroll
        for (int r = 0; r < 4; r++) {
            int k = w * 16 + r * 4 + q;
            out[t][r] = nbr[rbase[t] + (k > 124 ? 124 : k)];
        }
    }
}

// Refill bank BANK with the 2-tap group whose window-local first tap is C0
// (compile-time) and global first tap is k0 (runtime; taps >124 masked).
template<int BANK, int C0>
__device__ __forceinline__ void
refill(short8 (&A)[2][2][4], short8 (&B)[2][2][2], int k0, const int (&nb)[4][4],
       const unsigned short* __restrict__ xb, const unsigned short* __restrict__ wf,
       int m, int q, int lane) {
    #pragma unroll
    for (int jj = 0; jj < 2; jj++) {
        const int c = C0 + jj;                    // compile-time
        int k = k0 + jj;                          // runtime
        int kc = k > 124 ? 124 : k;
        B[BANK][jj][0] = *(const short8*)(wf + (size_t)(kc * 128 + lane) * 8);
        B[BANK][jj][1] = *(const short8*)(wf + (size_t)(kc * 128 + 64 + lane) * 8);
        #pragma unroll
        for (int t = 0; t < 4; t++) {
            int idx = __shfl(nb[t][c >> 2], ((c & 3) << 4) | m, 64);
            if (k > 124) idx = -1;
            short8 a = {0, 0, 0, 0, 0, 0, 0, 0};
            if (idx >= 0) a = *(const short8*)(xb + (size_t)idx * CH + q * 8);
            A[BANK][jj][t] = a;
        }
    }
}

template<int BANK>
__device__ __forceinline__ void
consume(f32x4 (&acc)[4][2], const short8 (&A)[2][2][4], const short8 (&B)[2][2][2]) {
    #pragma unroll
    for (int jj = 0; jj < 2; jj++) {
        #pragma unroll
        for (int t = 0; t < 4; t++) {
            acc[t][0] = __builtin_amdgcn_mfma_f32_16x16x32_bf16(A[BANK][jj][t], B[BANK][jj][0], acc[t][0], 0, 0, 0);
            acc[t][1] = __builtin_amdgcn_mfma_f32_16x16x32_bf16(A[BANK][jj][t], B[BANK][jj][1], acc[t][1], 0, 0, 0);
        }
    }
}

// K2: gather-conv. Wave = 4 tiles of 16 voxels. Taps padded to 128, processed
// as 8 windows x 8 groups(2 taps), double-buffered refill distance 2.
__global__ __launch_bounds__(256, 2) void
k_conv(const unsigned short* __restrict__ xb, const int* __restrict__ nbr,
       const unsigned short* __restrict__ wf, float* __restrict__ co,
       float* __restrict__ stats) {
    const int lane = threadIdx.x & 63;
    const int wv = threadIdx.x >> 6;
    const int m = lane & 15;
    const int q = lane >> 4;
    const int vbase = (blockIdx.x * 4 + wv) * 64;

    f32x4 acc[4][2];
    #pragma unroll
    for (int t = 0; t < 4; t++)
        for (int h = 0; h < 2; h++)
            acc[t][h] = f32x4{0.f, 0.f, 0.f, 0.f};

    bool tval[4];
    int rbase[4];
    #pragma unroll
    for (int t = 0; t < 4; t++) {
        tval[t] = (vbase + t * 16) < NV;
        rbase[t] = tval[t] ? (vbase + t * 16 + m) * KT : 0;
    }

    short8 A[2][2][4];
    short8 B[2][2][2];
    int nb[4][4], nbn[4][4];

    load_nb(0, nbr, rbase, q, nb);
    refill<0, 0>(A, B, 0, nb, xb, wf, m, q, lane);
    refill<1, 2>(A, B, 2, nb, xb, wf, m, q, lane);

    for (int w = 0; w < 8; w++) {
        const int kb = w * 16;
        if (w < 7) load_nb(w + 1, nbr, rbase, q, nbn);
        consume<0>(acc, A, B); refill<0, 4>(A, B, kb + 4, nb, xb, wf, m, q, lane);
        consume<1>(acc, A, B); refill<1, 6>(A, B, kb + 6, nb, xb, wf, m, q, lane);
        consume<0>(acc, A, B); refill<0, 8>(A, B, kb + 8, nb, xb, wf, m, q, lane);
        consume<1>(acc, A, B); refill<1, 10>(A, B, kb + 10, nb, xb, wf, m, q, lane);
        consume<0>(acc, A, B); refill<0, 12>(A, B, kb + 12, nb, xb, wf, m, q, lane);
        consume<1>(acc, A, B); refill<1, 14>(A, B, kb + 14, nb, xb, wf, m, q, lane);
        consume<0>(acc, A, B); refill<0, 0>(A, B, kb + 16, nbn, xb, wf, m, q, lane);
        consume<1>(acc, A, B); refill<1, 2>(A, B, kb + 18, nbn, xb, wf, m, q, lane);
        #pragma unroll
        for (int t = 0; t < 4; t++)
            #pragma unroll
            for (int r = 0; r < 4; r++)
                nb[t][r] = nbn[t][r];
    }

    float s0 = 0.f, s1 = 0.f, q0 = 0.f, q1 = 0.f;
    #pragma unroll
    for (int t = 0; t < 4; t++) {
        if (!tval[t]) continue;
        int v0 = vbase + t * 16 + q * 4;
        #pragma unroll
        for (int r = 0; r < 4; r++) {
            float a0 = acc[t][0][r], a1 = acc[t][1][r];
            co[(size_t)(v0 + r) * CH + m] = a0;
            co[(size_t)(v0 + r) * CH + 16 + m] = a1;
            s0 += a0; q0 += a0 * a0;
            s1 += a1; q1 += a1 * a1;
        }
    }
    s0 += __shfl_xor(s0, 16); s0 += __shfl_xor(s0, 32);
    s1 += __shfl_xor(s1, 16); s1 += __shfl_xor(s1, 32);
    q0 += __shfl_xor(q0, 16); q0 += __shfl_xor(q0, 32);
    q1 += __shfl_xor(q1, 16); q1 += __shfl_xor(q1, 32);
    if (q == 0) {
        atomicAdd(&stats[m],      s0);
        atomicAdd(&stats[16 + m], s1);
        atomicAdd(&stats[32 + m], q0);
        atomicAdd(&stats[48 + m], q1);
    }
}

// K3: finalize BN scale/shift. stats[64..95]=scale, stats[96..127]=shift.
__global__ void k_final(const float* __restrict__ gamma, const float* __restrict__ beta,
                        float* __restrict__ stats) {
    int c = threadIdx.x;
    if (c < CH) {
        float mean = stats[c] * (1.0f / NV);
        float var = stats[32 + c] * (1.0f / NV) - mean * mean;
        float sc = gamma[c] * rsqrtf(var + EPSBN);
        stats[64 + c] = sc;
        stats[96 + c] = beta[c] - mean * sc;
    }
}

// K4: in-place BN + ELU + MFMA linear on d_out. Wave = one 16-voxel tile/iter.
// Load layout lane(m,q) <- row v0+m, ch q*8..+8 == A-fragment layout exactly.
__global__ __launch_bounds__(256) void
k_epi(float* __restrict__ io, const unsigned short* __restrict__ wl,
      const float* __restrict__ blin, const float* __restrict__ stats) {
    const int lane = threadIdx.x & 63;
    const int wv = threadIdx.x >> 6;
    const int m = lane & 15;
    const int q = lane >> 4;

    short8 wl0 = *(const short8*)(wl + (size_t)lane * 8);
    short8 wl1 = *(const short8*)(wl + (size_t)(64 + lane) * 8);
    float ssc8[8], ssh8[8];
    #pragma unroll
    for (int j = 0; j < 8; j++) {
        ssc8[j] = stats[64 + q * 8 + j];
        ssh8[j] = stats[96 + q * 8 + j];
    }
    float bias0 = blin[m];
    float bias1 = blin[16 + m];

    const int wstep = gridDim.x * 4;
    for (int tile = blockIdx.x * 4 + wv; tile < NTILES; tile += wstep) {
        const int v0 = tile * 16;
        const float* p = io + (size_t)(v0 + m) * CH + q * 8;
        float4 e0 = *(const float4*)p;
        float4 e1 = *(const float4*)(p + 4);
        float e[8] = {e0.x, e0.y, e0.z, e0.w, e1.x, e1.y, e1.z, e1.w};
        short8 a;
        #pragma unroll
        for (int j = 0; j < 8; j++) {
            float f = e[j] * ssc8[j] + ssh8[j];
            f = f > 0.0f ? f : (__expf(f) - 1.0f);      // ELU alpha=1
            a[j] = (short)f2bf(f);
        }
        f32x4 z = {0.f, 0.f, 0.f, 0.f};
        f32x4 d0 = __builtin_amdgcn_mfma_f32_16x16x32_bf16(a, wl0, z, 0, 0, 0);
        f32x4 d1 = __builtin_amdgcn_mfma_f32_16x16x32_bf16(a, wl1, z, 0, 0, 0);
        #pragma unroll
        for (int r = 0; r < 4; r++) {
            io[(size_t)(v0 + q * 4 + r) * CH + m]      = d0[r] + bias0;
            io[(size_t)(v0 + q * 4 + r) * CH + 16 + m] = d1[r] + bias1;
        }
    }
}

extern "C" void kernel_launch(void* const* d_in, const int* in_sizes, int n_in,
                              void* d_out, int out_size, void* d_ws, size_t ws_size,
                              hipStream_t stream) {
    const float* x     = (const float*)d_in[0];
    const int*   nbr   = (const int*)d_in[1];
    const float* Wc    = (const float*)d_in[2];
    // d_in[3] = b_conv: canceled by BN mean subtraction.
    const float* gamma = (const float*)d_in[4];
    const float* beta  = (const float*)d_in[5];
    const float* Wlin  = (const float*)d_in[6];
    const float* blin  = (const float*)d_in[7];
    float* out = (float*)d_out;

    char* ws = (char*)d_ws;
    unsigned short* xb = (unsigned short*)ws;                               // 32 MB
    size_t off = (size_t)NV * CH * 2;
    unsigned short* wf = (unsigned short*)(ws + off);                       // 256 KB
    off += (size_t)KT * 128 * 8 * 2;
    unsigned short* wl = (unsigned short*)(ws + off);                       // 2 KB
    off += 128 * 8 * 2;
    float* stats = (float*)(ws + off);                                      // 512 B

    int prep_blocks = (int)(((size_t)NV * CH / 8 + 255) / 256);             // 7813
    hipLaunchKernelGGL(k_prep, dim3(prep_blocks), dim3(256), 0, stream,
                       x, Wc, Wlin, xb, wf, wl, stats);
    hipLaunchKernelGGL(k_conv, dim3((NV + 255) / 256), dim3(256), 0, stream,
                       xb, nbr, wf, out, stats);
    hipLaunchKernelGGL(k_final, dim3(1), dim3(64), 0, stream, gamma, beta, stats);
    hipLaunchKernelGGL(k_epi, dim3(1024), dim3(256), 0, stream, out, wl, blin, stats);
}